// Round 3
// baseline (350.711 us; speedup 1.0000x reference)
//
#include <hip/hip_runtime.h>

// Gaunt tensor product via exact collapse of the S2-grid path to a
// 25x9x9 Gaunt tensor G (computed on-device from Y_in/Y_out/qw).
//
// Pipeline:
//   K0: G[k,i,j] = sum_p qw*Y_out[k,p]*Y_in[i,p]*Y_in[j,p]     (d_ws)
//   K1: projection (over m) + in-register Gaunt -> co           (into d_out)
//   K3: per-l3 C->C mix, in-place on d_out (block-exclusive region)
//
// Shapes:
//  x1,x2 : [N=2048][64][2][9] f32    W1,W2 : [3][3][64][64]
//  Wout  : [3][5][64][64]            out   : [N][3][64][25]

#define NN 2048

__host__ __device__ constexpr int l_of9(int i)  { return i < 1 ? 0 : (i < 4 ? 1 : 2); }
__host__ __device__ constexpr int l_of25(int k) { return k < 1 ? 0 : (k < 4 ? 1 : (k < 9 ? 2 : (k < 16 ? 3 : 4))); }
__host__ __device__ constexpr int iabs_(int v)  { return v < 0 ? -v : v; }

// Compile-time superset of nonzero real-Gaunt entries.
__host__ __device__ constexpr bool gmask(int k, int i, int j) {
    const int l3 = l_of25(k), m3 = k - l3 * l3 - l3;
    const int l1 = l_of9(i),  m1 = i - l1 * l1 - l1;
    const int l2 = l_of9(j),  m2 = j - l2 * l2 - l2;
    if (((l1 + l2 + l3) & 1) != 0) return false;
    if (l3 > l1 + l2 || l3 < iabs_(l1 - l2)) return false;
    const int am3 = iabs_(m3);
    return (am3 == iabs_(m1 + m2)) || (am3 == iabs_(m1 - m2));
}

// ---------------------------------------------------------------------------
// K0: compute G (25 x 9 x 9) into workspace.
// ---------------------------------------------------------------------------
__global__ __launch_bounds__(256) void gaunt_G_kernel(
    const float* __restrict__ Y_in, const float* __restrict__ Y_out,
    const float* __restrict__ qw, float* __restrict__ G)
{
    const int k = blockIdx.x;
    const int t = threadIdx.x;

    __shared__ float yis[9 * 780];
    __shared__ float yos[780];
    __shared__ float qf[780];
    __shared__ float psum[81 * 3];

    for (int idx = t; idx < 9 * 780; idx += 256) yis[idx] = Y_in[idx];
    for (int idx = t; idx < 780; idx += 256) {
        yos[idx] = Y_out[k * 780 + idx];
        qf[idx]  = qw[idx / 39];
    }
    __syncthreads();

    if (t < 243) {
        const int r = t / 3;
        const int s = t % 3;
        const int i = r / 9, j = r % 9;
        const float* yi = &yis[i * 780];
        const float* yj = &yis[j * 780];
        const int p0 = s * 260;
        float acc = 0.f;
        for (int p = p0; p < p0 + 260; ++p)
            acc = fmaf(qf[p] * yos[p], yi[p] * yj[p], acc);
        psum[r * 3 + s] = acc;
    }
    __syncthreads();

    if (t < 81)
        G[k * 81 + t] = psum[t * 3 + 0] + psum[t * 3 + 1] + psum[t * 3 + 2];
}

// ---------------------------------------------------------------------------
// K1: projection + Gaunt. Grid (256, 3): 8 n per block, branch = blockIdx.y.
// Block 256 thr = 4 waves. Lane = (c4 = lane>>3, n_loc = lane&7).
// Wave w covers c = w*16 + cg*8 + c4, cg in {0,1}.
// Writes co[n][b][c][k] into `co` (= d_out used as scratch).
// ---------------------------------------------------------------------------
__global__ __launch_bounds__(256) void proj_gaunt_kernel(
    const float* __restrict__ x1, const float* __restrict__ x2,
    const float* __restrict__ W1, const float* __restrict__ W2,
    const float* __restrict__ G, float* __restrict__ co)
{
    const int b     = blockIdx.y;
    const int n0    = blockIdx.x * 8;
    const int t     = threadIdx.x;
    const int lane  = t & 63;
    const int w     = t >> 6;
    const int n_loc = lane & 7;
    const int c4    = lane >> 3;

    // x rows padded to 19 floats: lane stride 19 mod 32 -> 8 distinct banks.
    __shared__ float xs1[8 * 8 * 19];   // [(m_l*8 + n_l)*19 + slot]
    __shared__ float xs2[8 * 8 * 19];
    __shared__ float ws1[3 * 8 * 64];   // [(l*8 + m_l)*64 + c]
    __shared__ float ws2[3 * 8 * 64];

    float acc1[2][9], acc2[2][9];
#pragma unroll
    for (int cg = 0; cg < 2; ++cg)
#pragma unroll
        for (int i = 0; i < 9; ++i) { acc1[cg][i] = 0.f; acc2[cg][i] = 0.f; }

    const int e1 = (b == 2) ? 1 : 0;
    const int e2 = (b == 1) ? 1 : 0;

    for (int mc = 0; mc < 8; ++mc) {
        // ---- stage x chunk: 8 n x 8 m x 18 floats per array ----
        for (int idx = t; idx < 1152; idx += 256) {
            const int n_l = idx / 144;
            const int r   = idx - n_l * 144;        // m_l*18 + slot
            const int m_l = r / 18;
            const int slot = r - m_l * 18;
            const size_t g = (size_t)(n0 + n_l) * 1152 + (size_t)mc * 144 + r;
            xs1[(m_l * 8 + n_l) * 19 + slot] = x1[g];
            xs2[(m_l * 8 + n_l) * 19 + slot] = x2[g];
        }
        // ---- stage W chunk: 3 l x 8 m x 64 c per array ----
        for (int idx = t; idx < 1536; idx += 256) {
            const int l   = idx >> 9;
            const int r   = idx & 511;
            const int m_l = r >> 6;
            const int c   = r & 63;
            const size_t g = (size_t)((b * 3 + l) * 64 + (mc * 8 + m_l)) * 64 + c;
            ws1[idx] = W1[g];
            ws2[idx] = W2[g];
        }
        __syncthreads();

#pragma unroll
        for (int cg = 0; cg < 2; ++cg) {
            const int c = w * 16 + cg * 8 + c4;
#pragma unroll
            for (int m_l = 0; m_l < 8; ++m_l) {
                const float* xr1 = &xs1[(m_l * 8 + n_loc) * 19];
                const float* xr2 = &xs2[(m_l * 8 + n_loc) * 19];
#pragma unroll
                for (int l = 0; l < 3; ++l) {
                    const float w1v = ws1[(l * 8 + m_l) * 64 + c];
                    const float w2v = ws2[(l * 8 + m_l) * 64 + c];
                    const int s1 = ((l & 1) ^ e1) * 9 + l * l;
                    const int s2 = ((l & 1) ^ e2) * 9 + l * l;
#pragma unroll
                    for (int ii = 0; ii <= 2 * l; ++ii) {
                        acc1[cg][l * l + ii] = fmaf(xr1[s1 + ii], w1v, acc1[cg][l * l + ii]);
                        acc2[cg][l * l + ii] = fmaf(xr2[s2 + ii], w2v, acc2[cg][l * l + ii]);
                    }
                }
            }
        }
        __syncthreads();
    }

    // ---- in-register Gaunt contraction, G via wave-uniform s_load ----
    const int n = n0 + n_loc;
#pragma unroll
    for (int cg = 0; cg < 2; ++cg) {
        const int c = w * 16 + cg * 8 + c4;
        float c1r[9], c2r[9];
#pragma unroll
        for (int i = 0; i < 9; ++i) {
            c1r[i] = acc1[cg][i] * 0.125f;
            c2r[i] = acc2[cg][i] * 0.125f;
        }
        float cov[25];
#pragma unroll
        for (int k = 0; k < 25; ++k) cov[k] = 0.f;
#pragma unroll
        for (int i = 0; i < 9; ++i) {
#pragma unroll
            for (int j = 0; j < 9; ++j) {
                const float p = c1r[i] * c2r[j];
#pragma unroll
                for (int k = 0; k < 25; ++k) {
                    if (gmask(k, i, j))
                        cov[k] = fmaf(G[k * 81 + i * 9 + j], p, cov[k]);
                }
            }
        }
        float* cop = co + ((size_t)(n * 3 + b) * 64 + c) * 25;
#pragma unroll
        for (int k = 0; k < 25; ++k) cop[k] = cov[k];
    }
}

// ---------------------------------------------------------------------------
// K3: output mix, in place on d_out. Grid (512, 3): 4 n per block.
// Block 256 thr; wave = n_loc, lane = c. Stage co tile -> barrier -> overwrite.
// ---------------------------------------------------------------------------
__global__ __launch_bounds__(256) void mix_kernel(
    const float* __restrict__ Wout, float* __restrict__ io)
{
    const int b     = blockIdx.y;
    const int n0    = blockIdx.x * 4;
    const int t     = threadIdx.x;
    const int n_loc = t >> 6;
    const int c     = t & 63;

    __shared__ float cs[4][64][28];   // rows 112B-aligned for b128 merge

    for (int idx = t; idx < 4 * 1600; idx += 256) {
        const int n_l = idx / 1600;
        const int r   = idx - n_l * 1600;
        const int d   = r / 25;
        const int k   = r - d * 25;
        cs[n_l][d][k] = io[((size_t)((n0 + n_l) * 3 + b) * 64 + d) * 25 + k];
    }
    __syncthreads();

    float acc[25];
#pragma unroll
    for (int k = 0; k < 25; ++k) acc[k] = 0.f;

    const float* Wb = Wout + (size_t)b * 5 * 4096 + c;
    for (int d = 0; d < 64; ++d) {
        float wv[5];
#pragma unroll
        for (int l3 = 0; l3 < 5; ++l3) wv[l3] = Wb[(l3 * 64 + d) * 64];
        const float* cr = &cs[n_loc][d][0];
#pragma unroll
        for (int k = 0; k < 25; ++k)
            acc[k] = fmaf(cr[k], wv[l_of25(k)], acc[k]);
    }

    float* op = io + ((size_t)((n0 + n_loc) * 3 + b) * 64 + c) * 25;
#pragma unroll
    for (int k = 0; k < 25; ++k) op[k] = acc[k] * 0.125f;
}

extern "C" void kernel_launch(void* const* d_in, const int* in_sizes, int n_in,
                              void* d_out, int out_size, void* d_ws, size_t ws_size,
                              hipStream_t stream) {
    const float* x1    = (const float*)d_in[0];
    const float* x2    = (const float*)d_in[1];
    const float* W1    = (const float*)d_in[2];
    const float* W2    = (const float*)d_in[3];
    const float* Wout  = (const float*)d_in[4];
    const float* Y_in  = (const float*)d_in[5];
    const float* Y_out = (const float*)d_in[6];
    const float* qw    = (const float*)d_in[7];
    float* outp = (float*)d_out;
    float* G    = (float*)d_ws;   // 2025 floats

    gaunt_G_kernel<<<25, 256, 0, stream>>>(Y_in, Y_out, qw, G);
    proj_gaunt_kernel<<<dim3(NN / 8, 3), 256, 0, stream>>>(x1, x2, W1, W2, G, outp);
    mix_kernel<<<dim3(NN / 4, 3), 256, 0, stream>>>(Wout, outp);
}

// Round 4
// 309.410 us; speedup vs baseline: 1.1335x; 1.1335x over previous
//
#include <hip/hip_runtime.h>

// Gaunt tensor product via exact collapse of the S2-grid path to a
// 25x9x9 Gaunt tensor G2 (computed on-device, stored transposed [i][j][k]).
//
// K0: G2[(i*9+j)*28+k] = sum_p qw*Y_out[k,p]*Y_in[i,p]*Y_in[j,p]   (d_ws)
// K1: projection over m (x via SGPR s_load, W via LDS float2 pairs)
//     + in-register Gaunt (G2 via s_load) -> co[n][b][k][c] in d_out
// K2: per-l3 C->C mix; co via s_load (d-contiguous), W per-lane from L2;
//     in-place overwrite of d_out with final [n][b][c][k]. No LDS/barriers.

#define NN 2048

__host__ __device__ constexpr int l_of9(int i)  { return i < 1 ? 0 : (i < 4 ? 1 : 2); }
__host__ __device__ constexpr int l_of25(int k) { return k < 1 ? 0 : (k < 4 ? 1 : (k < 9 ? 2 : (k < 16 ? 3 : 4))); }
__host__ __device__ constexpr int iabs_(int v)  { return v < 0 ? -v : v; }

// Compile-time superset of nonzero real-Gaunt entries.
__host__ __device__ constexpr bool gmask(int k, int i, int j) {
    const int l3 = l_of25(k), m3 = k - l3 * l3 - l3;
    const int l1 = l_of9(i),  m1 = i - l1 * l1 - l1;
    const int l2 = l_of9(j),  m2 = j - l2 * l2 - l2;
    if (((l1 + l2 + l3) & 1) != 0) return false;
    if (l3 > l1 + l2 || l3 < iabs_(l1 - l2)) return false;
    const int am3 = iabs_(m3);
    return (am3 == iabs_(m1 + m2)) || (am3 == iabs_(m1 - m2));
}

// ---------------------------------------------------------------------------
// K0: G2[(i*9+j)*28 + k]
// ---------------------------------------------------------------------------
__global__ __launch_bounds__(256) void gaunt_G_kernel(
    const float* __restrict__ Y_in, const float* __restrict__ Y_out,
    const float* __restrict__ qw, float* __restrict__ G2)
{
    const int k = blockIdx.x;      // 0..24
    const int t = threadIdx.x;

    __shared__ float yis[9 * 780];
    __shared__ float yos[780];
    __shared__ float qf[780];
    __shared__ float psum[81 * 3];

    for (int idx = t; idx < 9 * 780; idx += 256) yis[idx] = Y_in[idx];
    for (int idx = t; idx < 780; idx += 256) {
        yos[idx] = Y_out[k * 780 + idx];
        qf[idx]  = qw[idx / 39];
    }
    __syncthreads();

    if (t < 243) {
        const int r = t / 3;
        const int s = t % 3;
        const int i = r / 9, j = r % 9;
        const float* yi = &yis[i * 780];
        const float* yj = &yis[j * 780];
        const int p0 = s * 260;
        float acc = 0.f;
        for (int p = p0; p < p0 + 260; ++p)
            acc = fmaf(qf[p] * yos[p], yi[p] * yj[p], acc);
        psum[r * 3 + s] = acc;
    }
    __syncthreads();

    if (t < 81)
        G2[t * 28 + k] = psum[t * 3 + 0] + psum[t * 3 + 1] + psum[t * 3 + 2];
}

// ---------------------------------------------------------------------------
// K1: grid (NN/8, 3), block 256 = 4 waves. Wave handles (na, na+1), lane = c.
// x rows + G2 are wave-uniform -> scalar loads. W from LDS as (W1,W2) pairs.
// Writes co[n][b][k][c] into d_out.
// ---------------------------------------------------------------------------
__global__ __launch_bounds__(256) void proj_gaunt_kernel(
    const float* __restrict__ x1, const float* __restrict__ x2,
    const float* __restrict__ W1, const float* __restrict__ W2,
    const float* __restrict__ G2, float* __restrict__ co)
{
    const int b  = blockIdx.y;
    const int t  = threadIdx.x;
    const int c  = t & 63;
    const int w  = __builtin_amdgcn_readfirstlane((int)(t >> 6));   // 0..3
    const int na = blockIdx.x * 8 + 2 * w;                          // uniform

    __shared__ float2 ws[3 * 16 * 64];   // [(l*16+ml)*64 + c] -> (W1,W2)

    const int e1 = (b == 2) ? 1 : 0;
    const int e2 = (b == 1) ? 1 : 0;
    int o1[3], o2[3];
#pragma unroll
    for (int l = 0; l < 3; ++l) {
        o1[l] = ((l & 1) ^ e1) * 9 + l * l;   // uniform SGPR offsets
        o2[l] = ((l & 1) ^ e2) * 9 + l * l;
    }

    float a1[2][9], a2[2][9];
#pragma unroll
    for (int i = 0; i < 9; ++i) {
        a1[0][i] = 0.f; a1[1][i] = 0.f;
        a2[0][i] = 0.f; a2[1][i] = 0.f;
    }

    const float* xr1 = x1 + (size_t)na * 1152;   // [m][parity][9], m-major
    const float* xr2 = x2 + (size_t)na * 1152;

    for (int mc = 0; mc < 4; ++mc) {
        if (mc) __syncthreads();
        // stage 16-m chunk of W1/W2 as float2 pairs (coalesced in c)
        for (int idx = t; idx < 3072; idx += 256) {
            const int l  = idx >> 10;
            const int r  = idx & 1023;                 // ml*64 + cc
            const int gi = ((b * 3 + l) * 64 + (mc * 16 + (r >> 6))) * 64 + (r & 63);
            ws[idx] = make_float2(W1[gi], W2[gi]);
        }
        __syncthreads();

#pragma unroll
        for (int ml = 0; ml < 16; ++ml) {
            const int moff = (mc * 16 + ml) * 18;
            const float* r1a = xr1 + moff;
            const float* r1b = r1a + 1152;
            const float* r2a = xr2 + moff;
            const float* r2b = r2a + 1152;
#pragma unroll
            for (int l = 0; l < 3; ++l) {
                const float2 wp = ws[(l * 16 + ml) * 64 + c];
                const float* p1a = r1a + o1[l];
                const float* p1b = r1b + o1[l];
                const float* p2a = r2a + o2[l];
                const float* p2b = r2b + o2[l];
#pragma unroll
                for (int ii = 0; ii <= 2 * l; ++ii) {
                    a1[0][l * l + ii] = fmaf(p1a[ii], wp.x, a1[0][l * l + ii]);
                    a1[1][l * l + ii] = fmaf(p1b[ii], wp.x, a1[1][l * l + ii]);
                    a2[0][l * l + ii] = fmaf(p2a[ii], wp.y, a2[0][l * l + ii]);
                    a2[1][l * l + ii] = fmaf(p2b[ii], wp.y, a2[1][l * l + ii]);
                }
            }
        }
    }

    // ---- in-register Gaunt; G2 rows are uniform -> s_load ----
#pragma unroll
    for (int np = 0; np < 2; ++np) {
        float c1[9], c2[9];
#pragma unroll
        for (int i = 0; i < 9; ++i) {
            c1[i] = a1[np][i] * 0.125f;
            c2[i] = a2[np][i] * 0.125f;
        }
        float cov[25];
#pragma unroll
        for (int k = 0; k < 25; ++k) cov[k] = 0.f;
#pragma unroll
        for (int i = 0; i < 9; ++i) {
#pragma unroll
            for (int j = 0; j < 9; ++j) {
                const float pij = c1[i] * c2[j];
                const float* g = G2 + (i * 9 + j) * 28;
#pragma unroll
                for (int k = 0; k < 25; ++k)
                    if (gmask(k, i, j)) cov[k] = fmaf(g[k], pij, cov[k]);
            }
        }
        float* cop = co + ((size_t)(na + np) * 3 + b) * 1600 + c;
#pragma unroll
        for (int k = 0; k < 25; ++k) cop[k * 64] = cov[k];
    }
}

// ---------------------------------------------------------------------------
// K2: grid (NN/8, 3), block 256 = 4 waves, no LDS, no barriers.
// Wave handles (na, na+1, b): reads co[n][b][k][d] via scalar loads
// (d-contiguous float4), W per-lane coalesced from L2, writes final
// out[n][b][c][k] over the same region (read-all-then-write per wave).
// ---------------------------------------------------------------------------
__global__ __launch_bounds__(256) void mix_kernel(
    const float* __restrict__ Wout, float* __restrict__ io)
{
    const int b  = blockIdx.y;
    const int t  = threadIdx.x;
    const int c  = t & 63;
    const int w  = __builtin_amdgcn_readfirstlane((int)(t >> 6));
    const int na = blockIdx.x * 8 + 2 * w;

    const float* Wb  = Wout + (size_t)b * 5 * 4096 + c;
    const float* coa = io + ((size_t)na * 3 + b) * 1600;   // [k][d]
    const float* cob = coa + 4800;                          // n = na+1

    float acc[2][25];
#pragma unroll
    for (int k = 0; k < 25; ++k) { acc[0][k] = 0.f; acc[1][k] = 0.f; }

    for (int dc = 0; dc < 16; ++dc) {
        const int d0 = dc * 4;
        float wr[5][4];
#pragma unroll
        for (int l3 = 0; l3 < 5; ++l3)
#pragma unroll
            for (int q = 0; q < 4; ++q)
                wr[l3][q] = Wb[(size_t)(l3 * 64 + d0 + q) * 64];

#pragma unroll
        for (int k = 0; k < 25; ++k) {
            const int l3 = l_of25(k);
            const float4 va = *(const float4*)(coa + k * 64 + d0);
            const float4 vb = *(const float4*)(cob + k * 64 + d0);
            acc[0][k] = fmaf(va.x, wr[l3][0], acc[0][k]);
            acc[0][k] = fmaf(va.y, wr[l3][1], acc[0][k]);
            acc[0][k] = fmaf(va.z, wr[l3][2], acc[0][k]);
            acc[0][k] = fmaf(va.w, wr[l3][3], acc[0][k]);
            acc[1][k] = fmaf(vb.x, wr[l3][0], acc[1][k]);
            acc[1][k] = fmaf(vb.y, wr[l3][1], acc[1][k]);
            acc[1][k] = fmaf(vb.z, wr[l3][2], acc[1][k]);
            acc[1][k] = fmaf(vb.w, wr[l3][3], acc[1][k]);
        }
    }

#pragma unroll
    for (int np = 0; np < 2; ++np) {
        float* op = io + (((size_t)(na + np) * 3 + b) * 64 + c) * 25;
#pragma unroll
        for (int k = 0; k < 25; ++k) op[k] = acc[np][k] * 0.125f;
    }
}

extern "C" void kernel_launch(void* const* d_in, const int* in_sizes, int n_in,
                              void* d_out, int out_size, void* d_ws, size_t ws_size,
                              hipStream_t stream) {
    const float* x1    = (const float*)d_in[0];
    const float* x2    = (const float*)d_in[1];
    const float* W1    = (const float*)d_in[2];
    const float* W2    = (const float*)d_in[3];
    const float* Wout  = (const float*)d_in[4];
    const float* Y_in  = (const float*)d_in[5];
    const float* Y_out = (const float*)d_in[6];
    const float* qw    = (const float*)d_in[7];
    float* outp = (float*)d_out;
    float* G2   = (float*)d_ws;   // 81*28 floats

    gaunt_G_kernel<<<25, 256, 0, stream>>>(Y_in, Y_out, qw, G2);
    proj_gaunt_kernel<<<dim3(NN / 8, 3), 256, 0, stream>>>(x1, x2, W1, W2, G2, outp);
    mix_kernel<<<dim3(NN / 8, 3), 256, 0, stream>>>(Wout, outp);
}

// Round 5
// 157.796 us; speedup vs baseline: 2.2226x; 1.9608x over previous
//
#include <hip/hip_runtime.h>
#include <utility>

// Gaunt tensor product via exact collapse of the S2-grid path to a sparse
// packed Gaunt tensor (computed on-device from Y_in/Y_out/qw).
//
// K0: per (i,j) pair: G_row[k] = sum_p qw*Y_out[k,p]*Y_in[i,p]*Y_in[j,p],
//     packed into gp[] using compile-time sparsity tables (d_ws).
// K1: fused projection (x via aligned float4 broadcast loads, W via LDS)
//     + in-register sparse Gaunt + C->C mix (LDS lane exchange) + coalesced
//     stores. One block = 4 n x 1 branch, 256 threads, lane = c.

#define NN 2048

__host__ __device__ constexpr int l_of9(int i)  { return i < 1 ? 0 : (i < 4 ? 1 : 2); }
__host__ __device__ constexpr int l_of25(int k) { return k < 1 ? 0 : (k < 4 ? 1 : (k < 9 ? 2 : (k < 16 ? 3 : 4))); }
__host__ __device__ constexpr int iabs_(int v)  { return v < 0 ? -v : v; }

// Compile-time superset of nonzero real-Gaunt entries (triangle, parity,
// |m3| in {|m1+m2|,|m1-m2|}). Entries outside are exactly zero in the
// reference's discrete quadrature (GL-beta exact to deg 39; alpha freqs < 19).
__host__ __device__ constexpr bool gmask(int k, int i, int j) {
    const int l3 = l_of25(k), m3 = k - l3 * l3 - l3;
    const int l1 = l_of9(i),  m1 = i - l1 * l1 - l1;
    const int l2 = l_of9(j),  m2 = j - l2 * l2 - l2;
    if (((l1 + l2 + l3) & 1) != 0) return false;
    if (l3 > l1 + l2 || l3 < iabs_(l1 - l2)) return false;
    const int am3 = iabs_(m3);
    return (am3 == iabs_(m1 + m2)) || (am3 == iabs_(m1 - m2));
}

// Compile-time packing tables: per (i,j) pair, the masked k-list, packed
// 4-aligned so f4 loads work.
struct GTab {
    int po[82];
    int pc[81];
    int kl[81][12];
    constexpr GTab() : po{}, pc{}, kl{} {
        int off = 0;
        for (int ij = 0; ij < 81; ++ij) {
            po[ij] = off;
            const int i = ij / 9, j = ij % 9;
            int cnum = 0;
            for (int k = 0; k < 25; ++k)
                if (gmask(k, i, j)) kl[ij][cnum++] = k;
            pc[ij] = cnum;
            off += (cnum + 3) & ~3;
        }
        po[81] = off;
    }
};
constexpr GTab GT{};

// ---------------------------------------------------------------------------
// K0: compute + pack G. Grid 81 (one block per (i,j)), 256 threads.
// ---------------------------------------------------------------------------
__global__ __launch_bounds__(256) void gaunt_pack_kernel(
    const float* __restrict__ Y_in, const float* __restrict__ Y_out,
    const float* __restrict__ qw, float* __restrict__ gp)
{
    const int ij = blockIdx.x;
    const int i = ij / 9, j = ij % 9;
    const int t = threadIdx.x;

    __shared__ float yy[780];
    __shared__ float ps[25][8];
    __shared__ float gr[25];

    for (int p = t; p < 780; p += 256)
        yy[p] = Y_in[i * 780 + p] * Y_in[j * 780 + p] * qw[p / 39];
    __syncthreads();

    if (t < 200) {
        const int k = t >> 3, s = t & 7;
        const float* yo = Y_out + k * 780;
        const int p1 = (s * 98 + 98 < 780) ? (s * 98 + 98) : 780;
        float a = 0.f;
        for (int p = s * 98; p < p1; ++p) a = fmaf(yy[p], yo[p], a);
        ps[k][s] = a;
    }
    __syncthreads();

    if (t < 25) {
        float a = 0.f;
#pragma unroll
        for (int s = 0; s < 8; ++s) a += ps[t][s];
        gr[t] = a;
    }
    __syncthreads();

    const int cntp = (GT.pc[ij] + 3) & ~3;
    if (t < cntp)
        gp[GT.po[ij] + t] = (t < GT.pc[ij]) ? gr[GT.kl[ij][t]] : 0.f;
}

// ---------------------------------------------------------------------------
// Sparse in-register Gaunt contraction with compile-time indices.
// ---------------------------------------------------------------------------
template <int IJ, int... Ts>
__device__ __forceinline__ void gaunt_apply(const float (&g)[12], float pij,
    float (&cov)[25], std::integer_sequence<int, Ts...>)
{
    ((cov[GT.kl[IJ][Ts]] = fmaf(g[Ts], pij, cov[GT.kl[IJ][Ts]])), ...);
}

template <int IJ>
__device__ __forceinline__ void gaunt_pair(const float* __restrict__ gp,
    const float (&c1)[9], const float (&c2)[9], float (&cov)[25])
{
    constexpr int cnt = GT.pc[IJ];
    if constexpr (cnt > 0) {
        constexpr int base = GT.po[IJ];
        constexpr int nv = (cnt + 3) / 4;
        const float pij = c1[IJ / 9] * c2[IJ % 9];
        float g[12];
#pragma unroll
        for (int q = 0; q < nv; ++q) {
            const float4 v = ((const float4*)(gp + base))[q];
            g[4 * q] = v.x; g[4 * q + 1] = v.y; g[4 * q + 2] = v.z; g[4 * q + 3] = v.w;
        }
        gaunt_apply<IJ>(g, pij, cov, std::make_integer_sequence<int, cnt>{});
    }
}

template <int I, int... Js>
__device__ __forceinline__ void gaunt_row(const float* __restrict__ gp,
    const float (&c1)[9], const float (&c2)[9], float (&cov)[25],
    std::integer_sequence<int, Js...>)
{
    (gaunt_pair<I * 9 + Js>(gp, c1, c2, cov), ...);
    __builtin_amdgcn_sched_barrier(0);   // bound live ranges per row
}

template <int... Is>
__device__ __forceinline__ void gaunt_all(const float* __restrict__ gp,
    const float (&c1)[9], const float (&c2)[9], float (&cov)[25],
    std::integer_sequence<int, Is...>)
{
    (gaunt_row<Is>(gp, c1, c2, cov, std::make_integer_sequence<int, 9>{}), ...);
}

// ---------------------------------------------------------------------------
// K1 body, specialized on parity selectors (compile-time x offsets).
// Block: 256 thr = 4 waves; wave w owns n = bx*4+w; lane = c.
// ---------------------------------------------------------------------------
template <int E1, int E2>
__device__ __forceinline__ void fused_body(
    const float* __restrict__ x1, const float* __restrict__ x2,
    const float* __restrict__ W1, const float* __restrict__ W2,
    const float* __restrict__ Wout, const float* __restrict__ gp,
    float* __restrict__ out, char* smem, int b)
{
    const int t = threadIdx.x;
    const int c = t & 63;
    const int w = t >> 6;
    const int n = blockIdx.x * 4 + w;

    float2* ws = (float2*)smem;               // 3*16*64 float2 = 24576 B (proj)
    float*  cs2 = (float*)smem;               // 4*1600 f32 = 25600 B (store stage)
    float*  cs  = (float*)(smem + 25600);     // 4*64*20 f32 = 20480 B (mix)

    const float* x1n = x1 + (size_t)n * 1152;
    const float* x2n = x2 + (size_t)n * 1152;

    float a1[9] = {0,0,0,0,0,0,0,0,0};
    float a2[9] = {0,0,0,0,0,0,0,0,0};

    // ---- projection over m (4 chunks of 16 m) ----
    for (int mc = 0; mc < 4; ++mc) {
        if (mc) __syncthreads();
        for (int idx = t; idx < 3072; idx += 256) {
            const int l = idx >> 10;
            const int r = idx & 1023;
            const int gi = ((b * 3 + l) * 64 + (mc * 16 + (r >> 6))) * 64 + (r & 63);
            ws[idx] = make_float2(W1[gi], W2[gi]);
        }
        __syncthreads();

#pragma unroll 1
        for (int mp = 0; mp < 8; ++mp) {
            const int m0 = mc * 16 + mp * 2;
            const float4* p1 = (const float4*)(x1n + m0 * 18);
            const float4* p2 = (const float4*)(x2n + m0 * 18);
            float xs1[36], xs2[36];
#pragma unroll
            for (int q = 0; q < 9; ++q) {
                const float4 t1 = p1[q], t2 = p2[q];
                xs1[4*q] = t1.x; xs1[4*q+1] = t1.y; xs1[4*q+2] = t1.z; xs1[4*q+3] = t1.w;
                xs2[4*q] = t2.x; xs2[4*q+1] = t2.y; xs2[4*q+2] = t2.z; xs2[4*q+3] = t2.w;
            }
            float2 wv[3][2];
#pragma unroll
            for (int l = 0; l < 3; ++l)
#pragma unroll
                for (int mi = 0; mi < 2; ++mi)
                    wv[l][mi] = ws[(l * 16 + mp * 2 + mi) * 64 + c];
#pragma unroll
            for (int l = 0; l < 3; ++l) {
                const int O1 = ((l & 1) ^ E1) * 9 + l * l;
                const int O2 = ((l & 1) ^ E2) * 9 + l * l;
#pragma unroll
                for (int mi = 0; mi < 2; ++mi)
#pragma unroll
                    for (int ii = 0; ii <= 2 * l; ++ii) {
                        a1[l*l+ii] = fmaf(xs1[O1 + 18*mi + ii], wv[l][mi].x, a1[l*l+ii]);
                        a2[l*l+ii] = fmaf(xs2[O2 + 18*mi + ii], wv[l][mi].y, a2[l*l+ii]);
                    }
            }
        }
    }
    __syncthreads();   // ws dead -> region reusable as cs2

    float c1[9], c2[9];
#pragma unroll
    for (int i = 0; i < 9; ++i) { c1[i] = a1[i] * 0.125f; c2[i] = a2[i] * 0.125f; }

    float cov[25] = {0,0,0,0,0,0,0,0,0,0,0,0,0,0,0,0,0,0,0,0,0,0,0,0,0};
    gaunt_all(gp, c1, c2, cov, std::make_integer_sequence<int, 9>{});

    // ---- mix: out[c,k] = 0.125 * sum_d cov_d[k] * Wout[l3(k)][d][c] ----
    float* csw = cs + w * (64 * 20);          // wave-private
    const float* WoB = Wout + (size_t)b * 5 * 4096 + c;

    // half 0: k = 0..12  (l3 0..3)
#pragma unroll
    for (int kk = 0; kk < 13; ++kk) csw[c * 20 + kk] = cov[kk];
    float accA[13];
#pragma unroll
    for (int kk = 0; kk < 13; ++kk) accA[kk] = 0.f;
#pragma unroll 2
    for (int d = 0; d < 64; ++d) {
        const float4 cv0 = *(const float4*)&csw[d * 20 + 0];
        const float4 cv1 = *(const float4*)&csw[d * 20 + 4];
        const float4 cv2 = *(const float4*)&csw[d * 20 + 8];
        const float4 cv3 = *(const float4*)&csw[d * 20 + 12];
        const float wv0 = WoB[(0 * 64 + d) * 64];
        const float wv1 = WoB[(1 * 64 + d) * 64];
        const float wv2 = WoB[(2 * 64 + d) * 64];
        const float wv3 = WoB[(3 * 64 + d) * 64];
        accA[0]  = fmaf(cv0.x, wv0, accA[0]);
        accA[1]  = fmaf(cv0.y, wv1, accA[1]);
        accA[2]  = fmaf(cv0.z, wv1, accA[2]);
        accA[3]  = fmaf(cv0.w, wv1, accA[3]);
        accA[4]  = fmaf(cv1.x, wv2, accA[4]);
        accA[5]  = fmaf(cv1.y, wv2, accA[5]);
        accA[6]  = fmaf(cv1.z, wv2, accA[6]);
        accA[7]  = fmaf(cv1.w, wv2, accA[7]);
        accA[8]  = fmaf(cv2.x, wv2, accA[8]);
        accA[9]  = fmaf(cv2.y, wv3, accA[9]);
        accA[10] = fmaf(cv2.z, wv3, accA[10]);
        accA[11] = fmaf(cv2.w, wv3, accA[11]);
        accA[12] = fmaf(cv3.x, wv3, accA[12]);
    }
#pragma unroll
    for (int kk = 0; kk < 13; ++kk)
        cs2[w * 1600 + c * 25 + kk] = accA[kk] * 0.125f;

    // half 1: k = 13..24 (l3 3..4)
#pragma unroll
    for (int kk = 0; kk < 12; ++kk) csw[c * 20 + kk] = cov[13 + kk];
    float accB[12];
#pragma unroll
    for (int kk = 0; kk < 12; ++kk) accB[kk] = 0.f;
#pragma unroll 2
    for (int d = 0; d < 64; ++d) {
        const float4 cv0 = *(const float4*)&csw[d * 20 + 0];
        const float4 cv1 = *(const float4*)&csw[d * 20 + 4];
        const float4 cv2 = *(const float4*)&csw[d * 20 + 8];
        const float wv3 = WoB[(3 * 64 + d) * 64];
        const float wv4 = WoB[(4 * 64 + d) * 64];
        accB[0]  = fmaf(cv0.x, wv3, accB[0]);
        accB[1]  = fmaf(cv0.y, wv3, accB[1]);
        accB[2]  = fmaf(cv0.z, wv3, accB[2]);
        accB[3]  = fmaf(cv0.w, wv4, accB[3]);
        accB[4]  = fmaf(cv1.x, wv4, accB[4]);
        accB[5]  = fmaf(cv1.y, wv4, accB[5]);
        accB[6]  = fmaf(cv1.z, wv4, accB[6]);
        accB[7]  = fmaf(cv1.w, wv4, accB[7]);
        accB[8]  = fmaf(cv2.x, wv4, accB[8]);
        accB[9]  = fmaf(cv2.y, wv4, accB[9]);
        accB[10] = fmaf(cv2.z, wv4, accB[10]);
        accB[11] = fmaf(cv2.w, wv4, accB[11]);
    }
#pragma unroll
    for (int kk = 0; kk < 12; ++kk)
        cs2[w * 1600 + c * 25 + 13 + kk] = accB[kk] * 0.125f;

    // ---- coalesced store via wave-private LDS transpose ----
    float* outn = out + ((size_t)n * 3 + b) * 1600;
#pragma unroll
    for (int r = 0; r < 6; ++r) {
        const float4 v = *(const float4*)&cs2[w * 1600 + r * 256 + c * 4];
        *(float4*)&outn[r * 256 + c * 4] = v;
    }
    outn[1536 + c] = cs2[w * 1600 + 1536 + c];
}

__global__ __launch_bounds__(256) void fused_kernel(
    const float* __restrict__ x1, const float* __restrict__ x2,
    const float* __restrict__ W1, const float* __restrict__ W2,
    const float* __restrict__ Wout, const float* __restrict__ gp,
    float* __restrict__ out)
{
    __shared__ __align__(16) char smem[46080];
    const int b = blockIdx.y;
    if (b == 0)      fused_body<0, 0>(x1, x2, W1, W2, Wout, gp, out, smem, 0);
    else if (b == 1) fused_body<0, 1>(x1, x2, W1, W2, Wout, gp, out, smem, 1);
    else             fused_body<1, 0>(x1, x2, W1, W2, Wout, gp, out, smem, 2);
}

extern "C" void kernel_launch(void* const* d_in, const int* in_sizes, int n_in,
                              void* d_out, int out_size, void* d_ws, size_t ws_size,
                              hipStream_t stream) {
    const float* x1    = (const float*)d_in[0];
    const float* x2    = (const float*)d_in[1];
    const float* W1    = (const float*)d_in[2];
    const float* W2    = (const float*)d_in[3];
    const float* Wout  = (const float*)d_in[4];
    const float* Y_in  = (const float*)d_in[5];
    const float* Y_out = (const float*)d_in[6];
    const float* qw    = (const float*)d_in[7];
    float* outp = (float*)d_out;
    float* gp   = (float*)d_ws;

    gaunt_pack_kernel<<<81, 256, 0, stream>>>(Y_in, Y_out, qw, gp);
    fused_kernel<<<dim3(NN / 4, 3), 256, 0, stream>>>(x1, x2, W1, W2, Wout, gp, outp);
}

// Round 6
// 141.615 us; speedup vs baseline: 2.4765x; 1.1143x over previous
//
#include <hip/hip_runtime.h>
#include <utility>

// Gaunt tensor product via exact collapse of the S2-grid path to a sparse
// packed Gaunt tensor (computed on-device from Y_in/Y_out/qw).
//
// K0: per (i,j): G_row[k] = sum_p qw*Y_out[k,p]*Y_in[i,p]*Y_in[j,p], packed.
// K1: fused. Block = 4 n x 1 branch, 256 thr, wave = n (uniform via
//     readfirstlane -> x rows + gp on the SCALAR pipe), lane = c.
//     W1/W2/Wout read per-lane direct (coalesced, L1/L2-resident).
//     LDS only for the mix-phase lane exchange (28.7 KB -> 5 blocks/CU).

#define NN 2048

__host__ __device__ constexpr int l_of9(int i)  { return i < 1 ? 0 : (i < 4 ? 1 : 2); }
__host__ __device__ constexpr int l_of25(int k) { return k < 1 ? 0 : (k < 4 ? 1 : (k < 9 ? 2 : (k < 16 ? 3 : 4))); }
__host__ __device__ constexpr int iabs_(int v)  { return v < 0 ? -v : v; }

__host__ __device__ constexpr bool gmask(int k, int i, int j) {
    const int l3 = l_of25(k), m3 = k - l3 * l3 - l3;
    const int l1 = l_of9(i),  m1 = i - l1 * l1 - l1;
    const int l2 = l_of9(j),  m2 = j - l2 * l2 - l2;
    if (((l1 + l2 + l3) & 1) != 0) return false;
    if (l3 > l1 + l2 || l3 < iabs_(l1 - l2)) return false;
    const int am3 = iabs_(m3);
    return (am3 == iabs_(m1 + m2)) || (am3 == iabs_(m1 - m2));
}

struct GTab {
    int po[82];
    int pc[81];
    int kl[81][12];
    constexpr GTab() : po{}, pc{}, kl{} {
        int off = 0;
        for (int ij = 0; ij < 81; ++ij) {
            po[ij] = off;
            const int i = ij / 9, j = ij % 9;
            int cnum = 0;
            for (int k = 0; k < 25; ++k)
                if (gmask(k, i, j)) kl[ij][cnum++] = k;
            pc[ij] = cnum;
            off += (cnum + 3) & ~3;
        }
        po[81] = off;
    }
};
constexpr GTab GT{};

// ---------------------------------------------------------------------------
// K0: compute + pack G. Grid 81, 256 threads.
// ---------------------------------------------------------------------------
__global__ __launch_bounds__(256) void gaunt_pack_kernel(
    const float* __restrict__ Y_in, const float* __restrict__ Y_out,
    const float* __restrict__ qw, float* __restrict__ gp)
{
    const int ij = blockIdx.x;
    const int i = ij / 9, j = ij % 9;
    const int t = threadIdx.x;

    __shared__ float yy[780];
    __shared__ float ps[25][8];
    __shared__ float gr[25];

    for (int p = t; p < 780; p += 256)
        yy[p] = Y_in[i * 780 + p] * Y_in[j * 780 + p] * qw[p / 39];
    __syncthreads();

    if (t < 200) {
        const int k = t >> 3, s = t & 7;
        const float* yo = Y_out + k * 780;
        const int p1 = (s * 98 + 98 < 780) ? (s * 98 + 98) : 780;
        float a = 0.f;
        for (int p = s * 98; p < p1; ++p) a = fmaf(yy[p], yo[p], a);
        ps[k][s] = a;
    }
    __syncthreads();

    if (t < 25) {
        float a = 0.f;
#pragma unroll
        for (int s = 0; s < 8; ++s) a += ps[t][s];
        gr[t] = a;
    }
    __syncthreads();

    const int cntp = (GT.pc[ij] + 3) & ~3;
    if (t < cntp)
        gp[GT.po[ij] + t] = (t < GT.pc[ij]) ? gr[GT.kl[ij][t]] : 0.f;
}

// ---------------------------------------------------------------------------
// Sparse in-register Gaunt with compile-time indices (gp loads uniform).
// ---------------------------------------------------------------------------
template <int IJ, int... Ts>
__device__ __forceinline__ void gaunt_apply(const float (&g)[12], float pij,
    float (&cov)[25], std::integer_sequence<int, Ts...>)
{
    ((cov[GT.kl[IJ][Ts]] = fmaf(g[Ts], pij, cov[GT.kl[IJ][Ts]])), ...);
}

template <int IJ>
__device__ __forceinline__ void gaunt_pair(const float* __restrict__ gp,
    const float (&c1)[9], const float (&c2)[9], float (&cov)[25])
{
    constexpr int cnt = GT.pc[IJ];
    if constexpr (cnt > 0) {
        constexpr int base = GT.po[IJ];
        constexpr int nv = (cnt + 3) / 4;
        const float pij = c1[IJ / 9] * c2[IJ % 9];
        float g[12];
#pragma unroll
        for (int q = 0; q < nv; ++q) {
            const float4 v = ((const float4*)(gp + base))[q];
            g[4 * q] = v.x; g[4 * q + 1] = v.y; g[4 * q + 2] = v.z; g[4 * q + 3] = v.w;
        }
        gaunt_apply<IJ>(g, pij, cov, std::make_integer_sequence<int, cnt>{});
    }
}

template <int I, int... Js>
__device__ __forceinline__ void gaunt_row(const float* __restrict__ gp,
    const float (&c1)[9], const float (&c2)[9], float (&cov)[25],
    std::integer_sequence<int, Js...>)
{
    (gaunt_pair<I * 9 + Js>(gp, c1, c2, cov), ...);
    __builtin_amdgcn_sched_barrier(0);   // bound live ranges per row
}

template <int... Is>
__device__ __forceinline__ void gaunt_all(const float* __restrict__ gp,
    const float (&c1)[9], const float (&c2)[9], float (&cov)[25],
    std::integer_sequence<int, Is...>)
{
    (gaunt_row<Is>(gp, c1, c2, cov, std::make_integer_sequence<int, 9>{}), ...);
}

// ---------------------------------------------------------------------------
// K1 body. Wave w owns n = bx*4+w (uniform), lane = c.
// ---------------------------------------------------------------------------
template <int E1, int E2>
__device__ __forceinline__ void fused_body(
    const float* __restrict__ x1, const float* __restrict__ x2,
    const float* __restrict__ W1, const float* __restrict__ W2,
    const float* __restrict__ Wout, const float* __restrict__ gp,
    float* __restrict__ out, float* __restrict__ cs, int b)
{
    const int t = threadIdx.x;
    const int c = t & 63;
    const int w = __builtin_amdgcn_readfirstlane(t >> 6);   // uniform wave id
    const int n = blockIdx.x * 4 + w;                       // uniform

    const float* x1n = x1 + (size_t)n * 1152;   // uniform -> scalar loads
    const float* x2n = x2 + (size_t)n * 1152;
    const float* W1b = W1 + (size_t)b * 3 * 4096 + c;
    const float* W2b = W2 + (size_t)b * 3 * 4096 + c;

    float a1[9] = {0,0,0,0,0,0,0,0,0};
    float a2[9] = {0,0,0,0,0,0,0,0,0};

    // ---- projection over m: 32 iterations of 2 m ----
#pragma unroll 1
    for (int mp = 0; mp < 32; ++mp) {
        const float4* p1 = (const float4*)(x1n + mp * 36);
        const float4* p2 = (const float4*)(x2n + mp * 36);
        float xs1[36], xs2[36];
#pragma unroll
        for (int q = 0; q < 9; ++q) {
            const float4 t1 = p1[q], t2 = p2[q];
            xs1[4*q] = t1.x; xs1[4*q+1] = t1.y; xs1[4*q+2] = t1.z; xs1[4*q+3] = t1.w;
            xs2[4*q] = t2.x; xs2[4*q+1] = t2.y; xs2[4*q+2] = t2.z; xs2[4*q+3] = t2.w;
        }
        float w1v[3][2], w2v[3][2];
#pragma unroll
        for (int l = 0; l < 3; ++l)
#pragma unroll
            for (int mi = 0; mi < 2; ++mi) {
                const int moff = (l * 64 + mp * 2 + mi) * 64;
                w1v[l][mi] = W1b[moff];
                w2v[l][mi] = W2b[moff];
            }
#pragma unroll
        for (int l = 0; l < 3; ++l) {
            const int O1 = ((l & 1) ^ E1) * 9 + l * l;
            const int O2 = ((l & 1) ^ E2) * 9 + l * l;
#pragma unroll
            for (int mi = 0; mi < 2; ++mi)
#pragma unroll
                for (int ii = 0; ii <= 2 * l; ++ii) {
                    a1[l*l+ii] = fmaf(xs1[O1 + 18*mi + ii], w1v[l][mi], a1[l*l+ii]);
                    a2[l*l+ii] = fmaf(xs2[O2 + 18*mi + ii], w2v[l][mi], a2[l*l+ii]);
                }
        }
    }

    float c1[9], c2[9];
#pragma unroll
    for (int i = 0; i < 9; ++i) { c1[i] = a1[i] * 0.125f; c2[i] = a2[i] * 0.125f; }

    float cov[25] = {0,0,0,0,0,0,0,0,0,0,0,0,0,0,0,0,0,0,0,0,0,0,0,0,0};
    gaunt_all(gp, c1, c2, cov, std::make_integer_sequence<int, 9>{});

    // ---- mix: out[c,k] = 0.125 * sum_d cov_d[k] * Wout[l3(k)][d][c] ----
    float* csw = cs + w * (64 * 28);          // wave-private
#pragma unroll
    for (int kk = 0; kk < 25; ++kk) csw[c * 28 + kk] = cov[kk];

    const float* WoB = Wout + (size_t)b * 5 * 4096 + c;
    float acc[25];
#pragma unroll
    for (int kk = 0; kk < 25; ++kk) acc[kk] = 0.f;

#pragma unroll 1
    for (int d = 0; d < 64; ++d) {
        float row[28];
#pragma unroll
        for (int q = 0; q < 7; ++q) {
            const float4 v = *(const float4*)&csw[d * 28 + 4 * q];
            row[4*q] = v.x; row[4*q+1] = v.y; row[4*q+2] = v.z; row[4*q+3] = v.w;
        }
        float wv[5];
#pragma unroll
        for (int l3 = 0; l3 < 5; ++l3) wv[l3] = WoB[(l3 * 64 + d) * 64];
#pragma unroll
        for (int k = 0; k < 25; ++k)
            acc[k] = fmaf(row[k], wv[l_of25(k)], acc[k]);
    }

    float* op = out + (((size_t)n * 3 + b) * 64 + c) * 25;
#pragma unroll
    for (int k = 0; k < 25; ++k) op[k] = acc[k] * 0.125f;
}

__global__ __launch_bounds__(256, 5) void fused_kernel(
    const float* __restrict__ x1, const float* __restrict__ x2,
    const float* __restrict__ W1, const float* __restrict__ W2,
    const float* __restrict__ Wout, const float* __restrict__ gp,
    float* __restrict__ out)
{
    __shared__ __align__(16) float cs[4 * 64 * 28];   // 28672 B
    const int b = blockIdx.y;
    if (b == 0)      fused_body<0, 0>(x1, x2, W1, W2, Wout, gp, out, cs, 0);
    else if (b == 1) fused_body<0, 1>(x1, x2, W1, W2, Wout, gp, out, cs, 1);
    else             fused_body<1, 0>(x1, x2, W1, W2, Wout, gp, out, cs, 2);
}

extern "C" void kernel_launch(void* const* d_in, const int* in_sizes, int n_in,
                              void* d_out, int out_size, void* d_ws, size_t ws_size,
                              hipStream_t stream) {
    const float* x1    = (const float*)d_in[0];
    const float* x2    = (const float*)d_in[1];
    const float* W1    = (const float*)d_in[2];
    const float* W2    = (const float*)d_in[3];
    const float* Wout  = (const float*)d_in[4];
    const float* Y_in  = (const float*)d_in[5];
    const float* Y_out = (const float*)d_in[6];
    const float* qw    = (const float*)d_in[7];
    float* outp = (float*)d_out;
    float* gp   = (float*)d_ws;

    gaunt_pack_kernel<<<81, 256, 0, stream>>>(Y_in, Y_out, qw, gp);
    fused_kernel<<<dim3(NN / 4, 3), 256, 0, stream>>>(x1, x2, W1, W2, Wout, gp, outp);
}

// Round 7
// 140.202 us; speedup vs baseline: 2.5015x; 1.0101x over previous
//
#include <hip/hip_runtime.h>
#include <utility>

// Gaunt tensor product via exact collapse of the S2-grid path to a sparse
// packed Gaunt tensor (computed on-device from Y_in/Y_out/qw).
//
// K0: per (i,j): G_row[k] = sum_p qw*Y_out[k,p]*Y_in[i,p]*Y_in[j,p], packed.
// K1: proj+Gaunt. Block = 4 n x 1 branch, 256 thr, wave = n (uniform ->
//     x rows + gp on the SCALAR pipe), lane = c. ZERO LDS. Writes
//     co[n][b][k][d] into d_out (contiguous 256B per k-store, no write amp).
// K2: mix. 1 wave per (n,b). co rows via uniform s_load (scalar pipe,
//     SGPR-operand FMAs), Wout per-lane from L2. In-place overwrite of
//     d_out through an LDS transpose -> coalesced float4 stores.

#define NN 2048

__host__ __device__ constexpr int l_of9(int i)  { return i < 1 ? 0 : (i < 4 ? 1 : 2); }
__host__ __device__ constexpr int l_of25(int k) { return k < 1 ? 0 : (k < 4 ? 1 : (k < 9 ? 2 : (k < 16 ? 3 : 4))); }
__host__ __device__ constexpr int iabs_(int v)  { return v < 0 ? -v : v; }

__host__ __device__ constexpr bool gmask(int k, int i, int j) {
    const int l3 = l_of25(k), m3 = k - l3 * l3 - l3;
    const int l1 = l_of9(i),  m1 = i - l1 * l1 - l1;
    const int l2 = l_of9(j),  m2 = j - l2 * l2 - l2;
    if (((l1 + l2 + l3) & 1) != 0) return false;
    if (l3 > l1 + l2 || l3 < iabs_(l1 - l2)) return false;
    const int am3 = iabs_(m3);
    return (am3 == iabs_(m1 + m2)) || (am3 == iabs_(m1 - m2));
}

struct GTab {
    int po[82];
    int pc[81];
    int kl[81][12];
    constexpr GTab() : po{}, pc{}, kl{} {
        int off = 0;
        for (int ij = 0; ij < 81; ++ij) {
            po[ij] = off;
            const int i = ij / 9, j = ij % 9;
            int cnum = 0;
            for (int k = 0; k < 25; ++k)
                if (gmask(k, i, j)) kl[ij][cnum++] = k;
            pc[ij] = cnum;
            off += (cnum + 3) & ~3;
        }
        po[81] = off;
    }
};
constexpr GTab GT{};

// ---------------------------------------------------------------------------
// K0: compute + pack G. Grid 81, 256 threads.
// ---------------------------------------------------------------------------
__global__ __launch_bounds__(256) void gaunt_pack_kernel(
    const float* __restrict__ Y_in, const float* __restrict__ Y_out,
    const float* __restrict__ qw, float* __restrict__ gp)
{
    const int ij = blockIdx.x;
    const int i = ij / 9, j = ij % 9;
    const int t = threadIdx.x;

    __shared__ float yy[780];
    __shared__ float ps[25][8];
    __shared__ float gr[25];

    for (int p = t; p < 780; p += 256)
        yy[p] = Y_in[i * 780 + p] * Y_in[j * 780 + p] * qw[p / 39];
    __syncthreads();

    if (t < 200) {
        const int k = t >> 3, s = t & 7;
        const float* yo = Y_out + k * 780;
        const int p1 = (s * 98 + 98 < 780) ? (s * 98 + 98) : 780;
        float a = 0.f;
        for (int p = s * 98; p < p1; ++p) a = fmaf(yy[p], yo[p], a);
        ps[k][s] = a;
    }
    __syncthreads();

    if (t < 25) {
        float a = 0.f;
#pragma unroll
        for (int s = 0; s < 8; ++s) a += ps[t][s];
        gr[t] = a;
    }
    __syncthreads();

    const int cntp = (GT.pc[ij] + 3) & ~3;
    if (t < cntp)
        gp[GT.po[ij] + t] = (t < GT.pc[ij]) ? gr[GT.kl[ij][t]] : 0.f;
}

// ---------------------------------------------------------------------------
// Sparse in-register Gaunt with compile-time indices (gp loads uniform).
// ---------------------------------------------------------------------------
template <int IJ, int... Ts>
__device__ __forceinline__ void gaunt_apply(const float (&g)[12], float pij,
    float (&cov)[25], std::integer_sequence<int, Ts...>)
{
    ((cov[GT.kl[IJ][Ts]] = fmaf(g[Ts], pij, cov[GT.kl[IJ][Ts]])), ...);
}

template <int IJ>
__device__ __forceinline__ void gaunt_pair(const float* __restrict__ gp,
    const float (&c1)[9], const float (&c2)[9], float (&cov)[25])
{
    constexpr int cnt = GT.pc[IJ];
    if constexpr (cnt > 0) {
        constexpr int base = GT.po[IJ];
        constexpr int nv = (cnt + 3) / 4;
        const float pij = c1[IJ / 9] * c2[IJ % 9];
        float g[12];
#pragma unroll
        for (int q = 0; q < nv; ++q) {
            const float4 v = ((const float4*)(gp + base))[q];
            g[4 * q] = v.x; g[4 * q + 1] = v.y; g[4 * q + 2] = v.z; g[4 * q + 3] = v.w;
        }
        gaunt_apply<IJ>(g, pij, cov, std::make_integer_sequence<int, cnt>{});
    }
}

template <int I, int... Js>
__device__ __forceinline__ void gaunt_row(const float* __restrict__ gp,
    const float (&c1)[9], const float (&c2)[9], float (&cov)[25],
    std::integer_sequence<int, Js...>)
{
    (gaunt_pair<I * 9 + Js>(gp, c1, c2, cov), ...);
    __builtin_amdgcn_sched_barrier(0);   // bound live ranges per row
}

template <int... Is>
__device__ __forceinline__ void gaunt_all(const float* __restrict__ gp,
    const float (&c1)[9], const float (&c2)[9], float (&cov)[25],
    std::integer_sequence<int, Is...>)
{
    (gaunt_row<Is>(gp, c1, c2, cov, std::make_integer_sequence<int, 9>{}), ...);
}

// ---------------------------------------------------------------------------
// K1 body. Wave w owns n = bx*4+w (uniform), lane = c. No LDS.
// ---------------------------------------------------------------------------
template <int E1, int E2>
__device__ __forceinline__ void fused_body(
    const float* __restrict__ x1, const float* __restrict__ x2,
    const float* __restrict__ W1, const float* __restrict__ W2,
    const float* __restrict__ gp, float* __restrict__ out, int b)
{
    const int t = threadIdx.x;
    const int c = t & 63;
    const int w = __builtin_amdgcn_readfirstlane(t >> 6);   // uniform wave id
    const int n = blockIdx.x * 4 + w;                       // uniform

    const float* x1n = x1 + (size_t)n * 1152;   // uniform -> scalar loads
    const float* x2n = x2 + (size_t)n * 1152;
    const float* W1b = W1 + (size_t)b * 3 * 4096 + c;
    const float* W2b = W2 + (size_t)b * 3 * 4096 + c;

    float a1[9] = {0,0,0,0,0,0,0,0,0};
    float a2[9] = {0,0,0,0,0,0,0,0,0};

    // ---- projection over m: 32 iterations of 2 m ----
#pragma unroll 1
    for (int mp = 0; mp < 32; ++mp) {
        const float4* p1 = (const float4*)(x1n + mp * 36);
        const float4* p2 = (const float4*)(x2n + mp * 36);
        float xs1[36], xs2[36];
#pragma unroll
        for (int q = 0; q < 9; ++q) {
            const float4 t1 = p1[q], t2 = p2[q];
            xs1[4*q] = t1.x; xs1[4*q+1] = t1.y; xs1[4*q+2] = t1.z; xs1[4*q+3] = t1.w;
            xs2[4*q] = t2.x; xs2[4*q+1] = t2.y; xs2[4*q+2] = t2.z; xs2[4*q+3] = t2.w;
        }
        float w1v[3][2], w2v[3][2];
#pragma unroll
        for (int l = 0; l < 3; ++l)
#pragma unroll
            for (int mi = 0; mi < 2; ++mi) {
                const int moff = (l * 64 + mp * 2 + mi) * 64;
                w1v[l][mi] = W1b[moff];
                w2v[l][mi] = W2b[moff];
            }
#pragma unroll
        for (int l = 0; l < 3; ++l) {
            const int O1 = ((l & 1) ^ E1) * 9 + l * l;
            const int O2 = ((l & 1) ^ E2) * 9 + l * l;
#pragma unroll
            for (int mi = 0; mi < 2; ++mi)
#pragma unroll
                for (int ii = 0; ii <= 2 * l; ++ii) {
                    a1[l*l+ii] = fmaf(xs1[O1 + 18*mi + ii], w1v[l][mi], a1[l*l+ii]);
                    a2[l*l+ii] = fmaf(xs2[O2 + 18*mi + ii], w2v[l][mi], a2[l*l+ii]);
                }
        }
    }

    float c1[9], c2[9];
#pragma unroll
    for (int i = 0; i < 9; ++i) { c1[i] = a1[i] * 0.125f; c2[i] = a2[i] * 0.125f; }

    float cov[25] = {0,0,0,0,0,0,0,0,0,0,0,0,0,0,0,0,0,0,0,0,0,0,0,0,0};
    gaunt_all(gp, c1, c2, cov, std::make_integer_sequence<int, 9>{});

    // ---- store co[n][b][k][d=c]: 25 contiguous 256B wave-stores ----
    float* cob = out + ((size_t)n * 3 + b) * 1600 + c;
#pragma unroll
    for (int k = 0; k < 25; ++k) cob[k * 64] = cov[k];
}

__global__ __launch_bounds__(256, 6) void fused_kernel(
    const float* __restrict__ x1, const float* __restrict__ x2,
    const float* __restrict__ W1, const float* __restrict__ W2,
    const float* __restrict__ gp, float* __restrict__ out)
{
    const int b = blockIdx.y;
    if (b == 0)      fused_body<0, 0>(x1, x2, W1, W2, gp, out, 0);
    else if (b == 1) fused_body<0, 1>(x1, x2, W1, W2, gp, out, 1);
    else             fused_body<1, 0>(x1, x2, W1, W2, gp, out, 2);
}

// ---------------------------------------------------------------------------
// K2: mix, 1 wave per (n,b). co rows via uniform s_load; W per-lane; LDS
// transpose for coalesced float4 stores; in-place on d_out.
// ---------------------------------------------------------------------------
__global__ __launch_bounds__(64, 6) void mix_kernel(
    const float* __restrict__ Wout, float* __restrict__ io)
{
    const int n = blockIdx.x;
    const int b = blockIdx.y;
    const int c = threadIdx.x;   // 0..63

    __shared__ float st[1600];

    const float* cob = io + ((size_t)n * 3 + b) * 1600;   // [k][d]
    const float* WoB = Wout + (size_t)b * 5 * 4096 + c;

    float acc[25];
#pragma unroll
    for (int k = 0; k < 25; ++k) acc[k] = 0.f;

#pragma unroll 1
    for (int dc = 0; dc < 16; ++dc) {
        const int d0 = dc * 4;
        float wr[5][4];
#pragma unroll
        for (int l3 = 0; l3 < 5; ++l3)
#pragma unroll
            for (int q = 0; q < 4; ++q)
                wr[l3][q] = WoB[(size_t)(l3 * 64 + d0 + q) * 64];

#pragma unroll
        for (int kg = 0; kg < 5; ++kg) {
#pragma unroll
            for (int kk = 0; kk < 5; ++kk) {
                const int k = kg * 5 + kk;
                const int l3 = l_of25(k);
                const float4 cv = *(const float4*)(cob + k * 64 + d0);
                acc[k] = fmaf(cv.x, wr[l3][0], acc[k]);
                acc[k] = fmaf(cv.y, wr[l3][1], acc[k]);
                acc[k] = fmaf(cv.z, wr[l3][2], acc[k]);
                acc[k] = fmaf(cv.w, wr[l3][3], acc[k]);
            }
            __builtin_amdgcn_sched_barrier(0);   // keep s_load bursts small
        }
    }

    // ---- transpose [d=c][k] -> linear [c][k] in LDS, then float4 stores ----
#pragma unroll
    for (int k = 0; k < 25; ++k) st[c * 25 + k] = acc[k] * 0.125f;
    __syncthreads();

    float* op = io + ((size_t)n * 3 + b) * 1600;
#pragma unroll
    for (int r = 0; r < 6; ++r) {
        const float4 v = *(const float4*)&st[(r * 64 + c) * 4];
        *(float4*)(op + (r * 64 + c) * 4) = v;
    }
    if (c < 16) {
        const float4 v = *(const float4*)&st[(384 + c) * 4];
        *(float4*)(op + (384 + c) * 4) = v;
    }
}

extern "C" void kernel_launch(void* const* d_in, const int* in_sizes, int n_in,
                              void* d_out, int out_size, void* d_ws, size_t ws_size,
                              hipStream_t stream) {
    const float* x1    = (const float*)d_in[0];
    const float* x2    = (const float*)d_in[1];
    const float* W1    = (const float*)d_in[2];
    const float* W2    = (const float*)d_in[3];
    const float* Wout  = (const float*)d_in[4];
    const float* Y_in  = (const float*)d_in[5];
    const float* Y_out = (const float*)d_in[6];
    const float* qw    = (const float*)d_in[7];
    float* outp = (float*)d_out;
    float* gp   = (float*)d_ws;

    gaunt_pack_kernel<<<81, 256, 0, stream>>>(Y_in, Y_out, qw, gp);
    fused_kernel<<<dim3(NN / 4, 3), 256, 0, stream>>>(x1, x2, W1, W2, gp, outp);
    mix_kernel<<<dim3(NN, 3), 64, 0, stream>>>(Wout, outp);
}